// Round 1
// baseline (216.080 us; speedup 1.0000x reference)
//
#include <hip/hip_runtime.h>
#include <math.h>

// Problem constants
#define B_  4
#define C_  256
#define N_  4096
#define CK_ 32
#define CV_ 128

typedef __attribute__((ext_vector_type(8))) short short8;  // 8 bf16 = 4 VGPRs
typedef __attribute__((ext_vector_type(4))) float f32x4;   // MFMA C/D frag
typedef unsigned short u16;
typedef unsigned int   u32;

static constexpr float LOG2E = 1.4426950408889634f;

static __device__ __forceinline__ u16 f2bf(float f) {       // fp32 -> bf16 RNE
    u32 u = __float_as_uint(f);
    u = (u + 0x7FFFu + ((u >> 16) & 1u)) >> 16;
    return (u16)u;
}
static __device__ __forceinline__ float bf2f(u16 h) {
    return __uint_as_float(((u32)h) << 16);
}

// native 2^x (v_exp_f32). Guarded: builtin if available (compiler handles
// trans-op hazards), else inline asm with a belt-and-braces s_nop.
static __device__ __forceinline__ float fexp2(float x) {
#if __has_builtin(__builtin_amdgcn_exp2f)
    return __builtin_amdgcn_exp2f(x);
#else
    float r; asm("v_exp_f32 %0, %1\n\ts_nop 0" : "=v"(r) : "v"(x)); return r;
#endif
}
static __device__ __forceinline__ float frcp(float x) {
#if __has_builtin(__builtin_amdgcn_rcpf)
    return __builtin_amdgcn_rcpf(x);
#else
    float r; asm("v_rcp_f32 %0, %1\n\ts_nop 0" : "=v"(r) : "v"(x)); return r;
#endif
}
// pack two fp32 -> 2x bf16 (RNE), lo = a, hi = b
static __device__ __forceinline__ u32 cvt_pk_bf16(float a, float b) {
    u32 r; asm("v_cvt_pk_bf16_f32 %0, %1, %2" : "=v"(r) : "v"(a), "v"(b));
    return r;
}

// ---------------------------------------------------------------------------
// Kernel 0a: weight convert. W16[192][256] = [theta*log2e; phi; g] bf16,
// ow16[256][128] bf16. 81920 elements, grid 320x256.
// ---------------------------------------------------------------------------
__global__ __launch_bounds__(256) void wconv_kernel(
    const float* __restrict__ theta_w, const float* __restrict__ phi_w,
    const float* __restrict__ g_w,     const float* __restrict__ o_w,
    u16* __restrict__ W16, u16* __restrict__ ow16)
{
    const int idx = blockIdx.x * 256 + threadIdx.x;
    if (idx < 8192)        W16[idx] = f2bf(theta_w[idx] * LOG2E);
    else if (idx < 16384)  W16[idx] = f2bf(phi_w[idx - 8192]);
    else if (idx < 49152)  W16[idx] = f2bf(g_w[idx - 16384]);
    else                   ow16[idx - 49152] = f2bf(o_w[idx - 49152]);
}

// ---------------------------------------------------------------------------
// Kernel 0b: x [B][C][N] fp32 -> xT16 [B][N][C] bf16 (transpose + convert).
// 64x64 tiles via LDS. Grid (N/64, C/64, B), block 256.
// ---------------------------------------------------------------------------
__global__ __launch_bounds__(256) void xt_kernel(
    const float* __restrict__ x, u16* __restrict__ xT16)
{
    const int b = blockIdx.z, c0 = blockIdx.y * 64, n0 = blockIdx.x * 64;
    const int t = threadIdx.x;
    __shared__ float tile[64][65];

    const int cr = t >> 4, nc = (t & 15) * 4;
    #pragma unroll
    for (int it = 0; it < 4; ++it) {
        const float4 v = *(const float4*)(x + (size_t)(b * C_ + c0 + cr + it * 16) * N_ + n0 + nc);
        tile[cr + it * 16][nc + 0] = v.x; tile[cr + it * 16][nc + 1] = v.y;
        tile[cr + it * 16][nc + 2] = v.z; tile[cr + it * 16][nc + 3] = v.w;
    }
    __syncthreads();
    const int n = t >> 2, cg = (t & 3) * 16;
    union { u16 us[16]; uint4 u4[2]; } pk;
    #pragma unroll
    for (int e = 0; e < 16; ++e) pk.us[e] = f2bf(tile[cg + e][n]);
    uint4* dst = (uint4*)(xT16 + (size_t)(b * N_ + n0 + n) * C_ + c0 + cg);
    dst[0] = pk.u4[0]; dst[1] = pk.u4[1];
}

// ---------------------------------------------------------------------------
// Kernel 1: projections via MFMA (unchanged).
// ---------------------------------------------------------------------------
__global__ __launch_bounds__(256) void proj_mfma_kernel(
    const u16* __restrict__ xT16, const u16* __restrict__ W16,
    const float* __restrict__ theta_b, const float* __restrict__ phi_b,
    const float* __restrict__ g_b,
    u16* __restrict__ theta_t, u16* __restrict__ phi_t, u16* __restrict__ g16)
{
    const int b = blockIdx.y, n0 = blockIdx.x * 64;
    const int w = threadIdx.x >> 6, lane = threadIdx.x & 63;
    const int lr = lane & 15, q = lane >> 4;
    const f32x4 zf = {0.f, 0.f, 0.f, 0.f};

    // ---- theta/phi: wave w owns pixel m-tile w ----
    const u16* xrow = xT16 + (size_t)(b * N_ + n0 + w * 16 + lr) * C_;
    f32x4 acc[4];
    #pragma unroll
    for (int nt = 0; nt < 4; ++nt) acc[nt] = zf;
    for (int ks = 0; ks < 8; ++ks) {
        const short8 aX = *(const short8*)(xrow + ks * 32 + q * 8);
        #pragma unroll
        for (int nt = 0; nt < 4; ++nt) {
            const short8 bW = *(const short8*)(W16 + (size_t)(nt * 16 + lr) * C_ + ks * 32 + q * 8);
            acc[nt] = __builtin_amdgcn_mfma_f32_16x16x32_bf16(aX, bW, acc[nt], 0, 0, 0);
        }
    }
    #pragma unroll
    for (int nt = 0; nt < 4; ++nt) {
        const int o = nt * 16 + lr;
        #pragma unroll
        for (int reg = 0; reg < 4; ++reg) {
            const int n = n0 + w * 16 + q * 4 + reg;
            if (nt < 2)
                theta_t[(size_t)(b * N_ + n) * CK_ + o] = f2bf(acc[nt][reg] + theta_b[o] * LOG2E);
            else
                phi_t[(size_t)(b * N_ + n) * CK_ + (o - 32)] = f2bf(acc[nt][reg] + phi_b[o - 32]);
        }
    }

    // ---- g: wave w owns c m-tiles {2w, 2w+1}, processed sequentially ----
    #pragma unroll
    for (int mp = 0; mp < 2; ++mp) {
        const int crow = (w * 2 + mp) * 16;
        f32x4 ag[4];
        #pragma unroll
        for (int nt = 0; nt < 4; ++nt) ag[nt] = zf;
        for (int ks = 0; ks < 8; ++ks) {
            const short8 aW = *(const short8*)(W16 + (size_t)(64 + crow + lr) * C_ + ks * 32 + q * 8);
            #pragma unroll
            for (int nt = 0; nt < 4; ++nt) {
                const short8 bX = *(const short8*)(xT16 + (size_t)(b * N_ + n0 + nt * 16 + lr) * C_ + ks * 32 + q * 8);
                ag[nt] = __builtin_amdgcn_mfma_f32_16x16x32_bf16(aW, bX, ag[nt], 0, 0, 0);
            }
        }
        #pragma unroll
        for (int nt = 0; nt < 4; ++nt) {
            #pragma unroll
            for (int reg = 0; reg < 4; ++reg) {
                const int c = crow + q * 4 + reg;
                const int n = n0 + nt * 16 + lr;
                g16[(size_t)(b * CV_ + c) * N_ + n] = f2bf(ag[nt][reg] + g_b[c]);
            }
        }
    }
}

// ---------------------------------------------------------------------------
// Kernel 2: Z[b][j] = sum_i exp2(S[i][j]) via MFMA. Native v_exp_f32.
// ---------------------------------------------------------------------------
__global__ __launch_bounds__(256) void colstats_kernel(
    const u16* __restrict__ theta_t, const u16* __restrict__ phi_t,
    float* __restrict__ Z)
{
    const int b  = blockIdx.z;
    const int j0 = blockIdx.x * 32;
    const int istart = blockIdx.y * (N_ / 4);
    const int tid = threadIdx.x;
    const int wave = tid >> 6, lane = tid & 63;
    const int lr = lane & 15, q = lane >> 4;

    const int jW = j0 + (wave & 1) * 16;
    const short8 bF = *(const short8*)(phi_t + (size_t)(b * N_ + jW + lr) * CK_ + q * 8);

    const u16* thp = theta_t + (size_t)b * N_ * CK_;
    const f32x4 zero = {0.f, 0.f, 0.f, 0.f};
    float zacc = 0.f;
    for (int it = istart + (wave >> 1) * 16; it < istart + N_ / 4; it += 32) {
        const short8 aF = *(const short8*)(thp + (size_t)(it + lr) * CK_ + q * 8);
        f32x4 S = __builtin_amdgcn_mfma_f32_16x16x32_bf16(aF, bF, zero, 0, 0, 0);
        zacc += fexp2(S[0]) + fexp2(S[1]) + fexp2(S[2]) + fexp2(S[3]);
    }
    zacc += __shfl_xor(zacc, 16);
    zacc += __shfl_xor(zacc, 32);
    if (lane < 16) atomicAdd(&Z[(size_t)b * N_ + jW + lr], zacc);
}

// ---------------------------------------------------------------------------
// Kernel 3: fold 1/Z into g (in place, bf16). 8 elems/thread. v_rcp instead
// of full-precision divide (1 ulp; bf16 rounding dominates).
// ---------------------------------------------------------------------------
__global__ __launch_bounds__(256) void gscale_kernel(
    u16* __restrict__ g16, const float* __restrict__ Z)
{
    const size_t idx = ((size_t)blockIdx.x * 256 + threadIdx.x) * 8;
    const int n = (int)(idx & (N_ - 1));
    const int b = (int)(idx / ((size_t)CV_ * N_));
    uint4 raw = *(const uint4*)(g16 + idx);
    const float4 z0 = *(const float4*)(Z + (size_t)b * N_ + n);
    const float4 z1 = *(const float4*)(Z + (size_t)b * N_ + n + 4);
    const float zz[8] = {z0.x, z0.y, z0.z, z0.w, z1.x, z1.y, z1.z, z1.w};
    u16* pr = (u16*)&raw;
    union { u16 us[8]; uint4 u4; } pk;
    #pragma unroll
    for (int k = 0; k < 8; ++k) pk.us[k] = f2bf(bf2f(pr[k]) * frcp(zz[k]));
    *(uint4*)(g16 + idx) = pk.u4;
}

// ---------------------------------------------------------------------------
// Kernel 4: o_pre partial = sum_{j in half} gp[c][j] * exp2(S[i][j]).
// Grid (N/64, 2 j-halves, B) = 512 blocks, 512 threads (8 waves).
// Restructured:
//  * S^T via mfma(A=phi, B=theta): lane holds 4 CONSECUTIVE j for one i ->
//    E-store = 4x v_cvt_pk_bf16_f32 + 2x ds_write_b64 (vs 8 cvt + 8 b16).
//  * native v_exp_f32 for exp2 (kills the libcall VALU tail).
//  * PV tiling 32c x 32i per wave: E LDS reads halved (32KB/blk/chunk);
//    g-frag duplication absorbed by L1 (block shares one 16KB g slice).
//  * LDS slot swizzle: phys 8B-slot = slot ^ (row & 14) — even-bit XOR keeps
//    16B read pairs contiguous AND ordered; writes 4/bank, reads balanced.
// One barrier per 64-j chunk, double-buffered E, phi prefetched in regs.
// ---------------------------------------------------------------------------
__global__ __launch_bounds__(512, 4) void opre_kernel(
    const u16* __restrict__ theta_t, const u16* __restrict__ phi_t,
    const u16* __restrict__ g16, float* __restrict__ o_p0, float* __restrict__ o_p1)
{
    const int b = blockIdx.z, jh = blockIdx.y, i0 = blockIdx.x * 64;
    const int w = threadIdx.x >> 6, lane = threadIdx.x & 63;
    const int lr = lane & 15, q = lane >> 4;

    __shared__ u16 El[2][64 * 64];      // 2 x 8 KB, slot-swizzled [i][j]
    __shared__ float rp[16 * 132];      // epilogue repack tile

    // S^T role: wave computes j-tile jt (16 j) x i-half ih (32 i)
    const int jt = w & 3, ih = w >> 2;
    // theta B-frags (n = i), fixed per block
    const short8 bT0 = *(const short8*)(theta_t + (size_t)(b * N_ + i0 + ih * 32 + lr) * CK_ + q * 8);
    const short8 bT1 = *(const short8*)(theta_t + (size_t)(b * N_ + i0 + ih * 32 + 16 + lr) * CK_ + q * 8);

    // PV role: wave owns c-strip cg*32 (2 m-tiles) x i-half ig (2 n-tiles)
    const int cg = w & 3, ig = w >> 2;
    const u16* gb0 = g16 + (size_t)(b * CV_ + cg * 32 + lr) * N_;
    const u16* gb1 = gb0 + (size_t)16 * N_;
    const u16* pb  = phi_t + (size_t)(b * N_) * CK_;

    const f32x4 zf = {0.f, 0.f, 0.f, 0.f};
    f32x4 acc[2][2];                    // [mt][nt]
    #pragma unroll
    for (int mt = 0; mt < 2; ++mt)
        #pragma unroll
        for (int nt = 0; nt < 2; ++nt) acc[mt][nt] = zf;

    const int jstart = jh * (N_ / 2), jend = jstart + N_ / 2;
    short8 aP = *(const short8*)(pb + (size_t)(jstart + jt * 16 + lr) * CK_ + q * 8);
    int buf = 0;

    // precomputed swizzled LDS offsets (u16 units)
    const int sw  = lr & 14;
    const int wo0 = (ih * 32 + lr) * 64 + (((jt * 4 + q) ^ sw) << 2);   // S0 rows
    const int wo1 = wo0 + 16 * 64;                                      // S1 rows
    const int ro_row = (ig * 32 + lr) * 64;
    const int ro_s0  = (((q * 2) + 0) ^ sw) << 2;                       // ks=0
    const int ro_s1  = (((q * 2) + 8) ^ sw) << 2;                       // ks=1

    for (int j0 = jstart; j0 < jend; j0 += 64) {
        // g A-frags for this chunk (issue early; consumed after barrier)
        const short8 gA00 = *(const short8*)(gb0 + j0 + q * 8);
        const short8 gA01 = *(const short8*)(gb0 + j0 + 32 + q * 8);
        const short8 gA10 = *(const short8*)(gb1 + j0 + q * 8);
        const short8 gA11 = *(const short8*)(gb1 + j0 + 32 + q * 8);

        // S^T: lane gets col i = ih*32(+16) + lr, rows j = jt*16 + q*4 + reg
        const f32x4 S0 = __builtin_amdgcn_mfma_f32_16x16x32_bf16(aP, bT0, zf, 0, 0, 0);
        const f32x4 S1 = __builtin_amdgcn_mfma_f32_16x16x32_bf16(aP, bT1, zf, 0, 0, 0);

        // prefetch next chunk's phi frag (register double-buffer)
        const int jn = (j0 + 64 < jend) ? j0 + 64 : jstart;
        aP = *(const short8*)(pb + (size_t)(jn + jt * 16 + lr) * CK_ + q * 8);

        u16* Eb = El[buf];
        uint2 v0, v1;
        v0.x = cvt_pk_bf16(fexp2(S0[0]), fexp2(S0[1]));
        v0.y = cvt_pk_bf16(fexp2(S0[2]), fexp2(S0[3]));
        v1.x = cvt_pk_bf16(fexp2(S1[0]), fexp2(S1[1]));
        v1.y = cvt_pk_bf16(fexp2(S1[2]), fexp2(S1[3]));
        *(uint2*)(Eb + wo0) = v0;
        *(uint2*)(Eb + wo1) = v1;
        __syncthreads();

        // PV: acc[mt][nt] += g(c-tile mt) . E^T  (B-frag: n=i, k=j)
        #pragma unroll
        for (int nt = 0; nt < 2; ++nt) {
            const short8 bE0 = *(const short8*)(Eb + ro_row + nt * (16 * 64) + ro_s0);
            const short8 bE1 = *(const short8*)(Eb + ro_row + nt * (16 * 64) + ro_s1);
            acc[0][nt] = __builtin_amdgcn_mfma_f32_16x16x32_bf16(gA00, bE0, acc[0][nt], 0, 0, 0);
            acc[0][nt] = __builtin_amdgcn_mfma_f32_16x16x32_bf16(gA01, bE1, acc[0][nt], 0, 0, 0);
            acc[1][nt] = __builtin_amdgcn_mfma_f32_16x16x32_bf16(gA10, bE0, acc[1][nt], 0, 0, 0);
            acc[1][nt] = __builtin_amdgcn_mfma_f32_16x16x32_bf16(gA11, bE1, acc[1][nt], 0, 0, 0);
        }
        buf ^= 1;
    }

    // epilogue: repack [c][i] acc -> coalesced [n][cv] fp32 partial stores
    __syncthreads();
    float* op = (jh ? o_p1 : o_p0) + (size_t)(b * N_ + i0) * CV_;
    #pragma unroll
    for (int p = 0; p < 4; ++p) {
        if (ig == (p >> 1)) {
            const int nt = p & 1;
            #pragma unroll
            for (int mt = 0; mt < 2; ++mt)
                #pragma unroll
                for (int reg = 0; reg < 4; ++reg)
                    rp[lr * 132 + cg * 32 + mt * 16 + q * 4 + reg] = acc[mt][nt][reg];
        }
        __syncthreads();
        const int t = threadIdx.x;
        const int ir = t >> 5, cc = (t & 31) * 4;
        *(float4*)(op + (size_t)(p * 16 + ir) * CV_ + cc) = *(const float4*)(rp + ir * 132 + cc);
        __syncthreads();
    }
}

// ---------------------------------------------------------------------------
// Kernel 5: out = x + gamma * (o_w @ (o_p0 + o_p1) + o_b) via MFMA.
// Grid (N/32, B) = 512 blocks (2/CU), block 256 (4 waves). Wave w: oc
// m-tiles w*4..w*4+3 over a 32-pixel n-slice. cvt_pk packing.
// ---------------------------------------------------------------------------
__global__ __launch_bounds__(256) void final_mfma_kernel(
    const float* __restrict__ o_p0, const float* __restrict__ o_p1,
    const u16* __restrict__ ow16, const float* __restrict__ o_b,
    const float* __restrict__ gamma, const float* __restrict__ x,
    float* __restrict__ out)
{
    const int b = blockIdx.y, n0 = blockIdx.x * 32;
    const int w = threadIdx.x >> 6, lane = threadIdx.x & 63;
    const int lr = lane & 15, q = lane >> 4;
    const f32x4 zf = {0.f, 0.f, 0.f, 0.f};

    f32x4 acc[4][2];
    #pragma unroll
    for (int mt = 0; mt < 4; ++mt)
        #pragma unroll
        for (int nt = 0; nt < 2; ++nt) acc[mt][nt] = zf;

    const float* p0 = o_p0 + (size_t)(b * N_ + n0) * CV_;
    const float* p1 = o_p1 + (size_t)(b * N_ + n0) * CV_;

    for (int ks = 0; ks < 4; ++ks) {
        short8 bP[2];
        #pragma unroll
        for (int nt = 0; nt < 2; ++nt) {
            const size_t base = (size_t)(nt * 16 + lr) * CV_ + ks * 32 + q * 8;
            const float4 a0 = *(const float4*)(p0 + base);
            const float4 a1 = *(const float4*)(p0 + base + 4);
            const float4 c0 = *(const float4*)(p1 + base);
            const float4 c1 = *(const float4*)(p1 + base + 4);
            union { u32 u[4]; short8 s8; } pk;
            pk.u[0] = cvt_pk_bf16(a0.x + c0.x, a0.y + c0.y);
            pk.u[1] = cvt_pk_bf16(a0.z + c0.z, a0.w + c0.w);
            pk.u[2] = cvt_pk_bf16(a1.x + c1.x, a1.y + c1.y);
            pk.u[3] = cvt_pk_bf16(a1.z + c1.z, a1.w + c1.w);
            bP[nt] = pk.s8;
        }
        #pragma unroll
        for (int mt = 0; mt < 4; ++mt) {
            const short8 aW = *(const short8*)(ow16 + (size_t)((w * 4 + mt) * 16 + lr) * CV_ + ks * 32 + q * 8);
            #pragma unroll
            for (int nt = 0; nt < 2; ++nt)
                acc[mt][nt] = __builtin_amdgcn_mfma_f32_16x16x32_bf16(aW, bP[nt], acc[mt][nt], 0, 0, 0);
        }
    }

    const float gm = gamma[0];
    #pragma unroll
    for (int mt = 0; mt < 4; ++mt) {
        #pragma unroll
        for (int nt = 0; nt < 2; ++nt) {
            #pragma unroll
            for (int reg = 0; reg < 4; ++reg) {
                const int oc = (w * 4 + mt) * 16 + q * 4 + reg;
                const int n = n0 + nt * 16 + lr;
                const size_t off = (size_t)(b * C_ + oc) * N_ + n;
                out[off] = x[off] + gm * (acc[mt][nt][reg] + o_b[oc]);
            }
        }
    }
}

// ---------------------------------------------------------------------------
extern "C" void kernel_launch(void* const* d_in, const int* in_sizes, int n_in,
                              void* d_out, int out_size, void* d_ws, size_t ws_size,
                              hipStream_t stream)
{
    const float* x       = (const float*)d_in[0];
    const float* theta_w = (const float*)d_in[1];
    const float* theta_b = (const float*)d_in[2];
    const float* phi_w   = (const float*)d_in[3];
    const float* phi_b   = (const float*)d_in[4];
    const float* g_w     = (const float*)d_in[5];
    const float* g_b     = (const float*)d_in[6];
    const float* o_w     = (const float*)d_in[7];
    const float* o_b     = (const float*)d_in[8];
    const float* gamma   = (const float*)d_in[9];
    float* out = (float*)d_out;

    // workspace: xT16 8MB | W16 96KB | ow16 64KB | theta_t 1MB | phi_t 1MB |
    //            g16 4MB | Z 64KB | o_p0 8MB | o_p1 8MB   (~31 MB)
    u16* xT16    = (u16*)d_ws;
    u16* W16     = xT16 + (size_t)B_ * N_ * C_;
    u16* ow16    = W16 + 192 * C_;
    u16* theta_t = ow16 + C_ * CV_;
    u16* phi_t   = theta_t + (size_t)B_ * N_ * CK_;
    u16* g16     = phi_t + (size_t)B_ * N_ * CK_;
    float* Z     = (float*)(g16 + (size_t)B_ * CV_ * N_);
    float* o_p0  = Z + (size_t)B_ * N_;
    float* o_p1  = o_p0 + (size_t)B_ * N_ * CV_;

    hipMemsetAsync(Z, 0, (size_t)B_ * N_ * sizeof(float), stream);

    wconv_kernel<<<dim3(320), 256, 0, stream>>>(theta_w, phi_w, g_w, o_w, W16, ow16);
    xt_kernel<<<dim3(N_ / 64, C_ / 64, B_), 256, 0, stream>>>(x, xT16);
    proj_mfma_kernel<<<dim3(N_ / 64, B_), 256, 0, stream>>>(
        xT16, W16, theta_b, phi_b, g_b, theta_t, phi_t, g16);
    colstats_kernel<<<dim3(N_ / 32, 4, B_), 256, 0, stream>>>(theta_t, phi_t, Z);
    gscale_kernel<<<dim3((B_ * CV_ * N_) / 2048), 256, 0, stream>>>(g16, Z);
    opre_kernel<<<dim3(N_ / 64, 2, B_), 512, 0, stream>>>(theta_t, phi_t, g16, o_p0, o_p1);
    final_mfma_kernel<<<dim3(N_ / 32, B_), 256, 0, stream>>>(
        o_p0, o_p1, ow16, o_b, gamma, x, out);
}